// Round 14
// baseline (130.708 us; speedup 1.0000x reference)
//
#include <hip/hip_runtime.h>
#include <hip/hip_bf16.h>

#define F 1024
#define B_ROWS 16384

typedef short v8s __attribute__((ext_vector_type(8)));
typedef float v4f __attribute__((ext_vector_type(4)));
typedef unsigned short v8u __attribute__((ext_vector_type(8)));
typedef unsigned short ushort_t;

__device__ __forceinline__ unsigned short f2bf(float f) {
    unsigned int u = __builtin_bit_cast(unsigned int, f);
    u = (u + 0x7FFFu + ((u >> 16) & 1u)) >> 16;  // RNE
    return (unsigned short)u;
}

// async global->LDS, 16B per lane. LDS dest = wave-uniform base + lane*16.
__device__ __forceinline__ void gload_lds16(const ushort_t* g, ushort_t* l) {
    __builtin_amdgcn_global_load_lds(
        (const __attribute__((address_space(1))) unsigned int*)g,
        (__attribute__((address_space(3))) unsigned int*)l,
        16, 0, 0);
}

// Chunk (rb, cb) = 16-row x 32-col bf16 block stored [lane][8 bf16] in MFMA
// operand order: lane l -> row rb*16 + (l&15), cols cb*32 + (l>>4)*8..+8.
// One chunk = 1 KB. B = strictly upper-triangular W ((n,k) = w_{kn}, k<n).
// N-tile nt needs K < 128*(nt+1): 56% of the full-GEMM MACs.
//
// POISON LOG (keep forever):
//  - fused-sigmoid epilogue in gemm: CONVICTED (MfmaUtil 20->4.4%). Separate.
//  - __launch_bounds__(256,4): spill on the old ping-pong loop (r12);
//    NEUTRAL on the m97 loop (r22/round12, 128.2 vs 128.6). Not a lever.
//  - X-pack fused as per-wave fp32 loads+cvts on MFMA path (r17): FAILED.
//  - K-split jobs (r18): REGRESSION (extra prologue/epilogue, A re-reads).
//  - fp32-A staged via global_load_lds + post-LDS cvt_pk (r20/r21): FAILED
//    gemm 34->65us (cvt+extra ds_reads on critical path; 4KB/lane-stride
//    uncoalesced A-gather). X-pack amortizes conversion AND linearizes the
//    staging source -- it stays.
//
// r19 (WIN): m97 structure -- both operands via global_load_lds from packed
// chunks, zero per-wave global loads in the loop. gemm ~33us.
// r23/r24 (round 13 was an infra failure -- resubmitted unchanged):
// ring-3 staging + counted-vmcnt raw barrier. With 2 buffers the per-step
// __syncthreads MUST drain the staging just issued (~120cyc of MFMA cover
// vs ~400-500cyc L3/HBM latency = the exposed stall). Ring-3 stages t+2
// each step (~1.5 steps of cover); barrier waits vmcnt(4) so my 4 newest
// stage-gloads stay in flight (in-order retirement => t+1's 4 have
// landed). Slot t%3 is rewritten by STAGE(t+3) at step t+1, gated by the
// end-of-step-t barrier; ds_reads of step t are consumed (compiler lgkmcnt
// before MFMA) before that barrier. LDS 48KB -> (256,3).

// prep: [0,64) zero rowacc; [64,576) pack triangular B; [576,8768) pack X.
__global__ __launch_bounds__(256) void prep_kernel(
        const float* __restrict__ w, const float* __restrict__ x,
        ushort_t* __restrict__ Bp, ushort_t* __restrict__ Xp,
        float* __restrict__ acc) {
    const int bid  = blockIdx.x;
    const int tid  = threadIdx.x;
    const int lane = tid & 63;
    const int wave = tid >> 6;
    const int l16  = lane & 15;
    const int quad = lane >> 4;

    if (bid < 64) {
        acc[bid * 256 + tid] = 0.0f;
    } else if (bid < 576) {
        const int c  = (bid - 64) * 4 + wave;    // 0..2047
        const int n  = (c >> 5) * 16 + l16;      // output-col axis
        const int k0 = (c & 31) * 32 + quad * 8; // contraction axis
        v8u o;
#pragma unroll
        for (int e = 0; e < 8; ++e) {
            const int k = k0 + e;
            float v = 0.0f;
            if (k < n) {  // strictly upper: pair (k,n), k<n
                const int idx = k * (F - 1) - (k * (k - 1)) / 2 + (n - k - 1);
                v = w[idx];  // scattered read; w = 2MB, L2-resident
            }
            o[e] = f2bf(v);
        }
        *(v8u*)(Bp + (size_t)c * 512 + lane * 8) = o;
    } else {
        const int c  = (bid - 576) * 4 + wave;  // 0..32767
        const int r  = (c >> 5) * 16 + l16;     // X row
        const int k0 = (c & 31) * 32 + quad * 8;
        const float* src = x + (size_t)r * F + k0;
        float4 v0 = *(const float4*)(src);
        float4 v1 = *(const float4*)(src + 4);
        v8u o;
        o[0] = f2bf(v0.x); o[1] = f2bf(v0.y); o[2] = f2bf(v0.z); o[3] = f2bf(v0.w);
        o[4] = f2bf(v1.x); o[5] = f2bf(v1.y); o[6] = f2bf(v1.z); o[7] = f2bf(v1.w);
        *(v8u*)(Xp + (size_t)c * 512 + lane * 8) = o;
    }
}

// m97-structure GEMM, triangular-K, ring-3 staged (r23/r24).
// 128x128 block, 2x2 waves, K-step 32.
// LDS: 3 ring slots x (8 A-chunks + 8 B-chunks) x 1KB = 48 KB.
__global__ __launch_bounds__(256, 3) void gemm_kernel(
        const ushort_t* __restrict__ Xp,   // packed X chunks
        const ushort_t* __restrict__ Bp,   // packed triangular-W chunks
        const float*   __restrict__ Xf,    // fp32 X (epilogue)
        float*         __restrict__ rowacc) {
    __shared__ ushort_t Ls[3 * 16 * 512];  // [slot][chunk 0-7=A, 8-15=B][1KB]

    const int f   = blockIdx.x;          // 0..1023
    const int xcd = f & 7;
    const int g   = f >> 3;              // 0..127
    const int y   = g & 15;
    const int nt  = 7 - (g >> 4);        // heavy (nt=7) first
    const int blockM = (xcd * 16 + y) * 128;
    const int blockN = nt * 128;
    const int tEnd   = 4 * (nt + 1);     // K-steps of 32: K < 128*(nt+1)

    const int tid   = threadIdx.x;
    const int lane  = tid & 63;
    const int wave  = tid >> 6;
    const int waveM = wave >> 1;
    const int waveN = wave & 1;
    const int quad  = lane >> 4;
    const int l16   = lane & 15;

    const int mgBase = blockM >> 4;      // first A row-group (of 8)
    const int ngB    = nt * 8;           // first B row-group (of 8)

    // Staging: waves 0-1 stage the 8 A-chunks, waves 2-3 the 8 B-chunks.
    // Per wave 4 gload_lds16 per K-step; wave-uniform LDS dest + lane*16.
    const bool stageA = (wave < 2);
    const int  qBase  = (wave & 1) * 4;  // chunk offset within A or B half
    const ushort_t* gsrc0 = stageA
        ? Xp + ((size_t)(mgBase + qBase) * 32) * 512
        : Bp + ((size_t)(ngB  + qBase) * 32) * 512;
    const int slot0 = (stageA ? 0 : 8) + qBase;

#define STAGE(t, slot)                                                         \
    {                                                                          \
        _Pragma("unroll")                                                      \
        for (int q = 0; q < 4; ++q) {                                          \
            gload_lds16(gsrc0 + ((size_t)q * 32 + (t)) * 512 + lane * 8,       \
                        Ls + ((slot) * 16 + slot0 + q) * 512);                 \
        }                                                                      \
    }

    v4f acc[4][4];
#pragma unroll
    for (int i = 0; i < 4; i++)
#pragma unroll
        for (int j = 0; j < 4; j++) acc[i][j] = (v4f)(0.0f);

    v8s afr[4], bfr[4];

    // prologue: stage K-steps 0 and 1 (slots 0,1); full drain ONCE.
    STAGE(0, 0)
    STAGE(1, 1)
    __syncthreads();

    int sc = 0;  // t % 3: slot read this step
    int s2 = 2;  // (t+2) % 3: slot staged this step

    for (int t = 0; t < tEnd; ++t) {
        const bool more = (t + 1 < tEnd);
        const bool st2  = (t + 2 < tEnd);
        if (st2) STAGE(t + 2, s2)  // lands by end of step t+1

#pragma unroll
        for (int mi = 0; mi < 4; ++mi)
            afr[mi] = *(const v8s*)(Ls + (sc * 16 + waveM * 4 + mi) * 512 + lane * 8);
#pragma unroll
        for (int ni = 0; ni < 4; ++ni)
            bfr[ni] = *(const v8s*)(Ls + (sc * 16 + 8 + waveN * 4 + ni) * 512 + lane * 8);

#pragma unroll
        for (int mi = 0; mi < 4; ++mi)
#pragma unroll
            for (int ni = 0; ni < 4; ++ni)
                acc[mi][ni] = __builtin_amdgcn_mfma_f32_16x16x32_bf16(
                    afr[mi], bfr[ni], acc[mi][ni], 0, 0, 0);

        if (more) {
            // Gate slot reuse + publication of STAGE(t+1) (issued at step
            // t-1; all but my newest 4 vmem ops retired by vmcnt(4)).
            // STAGE(t+2) stays in flight across the barrier.
            if (st2) {
                asm volatile("s_waitcnt vmcnt(4)" ::: "memory");
            } else {
                asm volatile("s_waitcnt vmcnt(0)" ::: "memory");
            }
            __builtin_amdgcn_s_barrier();
        }

        sc = (sc == 2) ? 0 : sc + 1;
        s2 = (s2 == 2) ? 0 : s2 + 1;
    }
#undef STAGE

    // Epilogue: C/D mapping (verified): col = lane&15, row = quad*4 + reg.
#pragma unroll
    for (int mi = 0; mi < 4; mi++) {
#pragma unroll
        for (int r = 0; r < 4; r++) {
            const int b = blockM + waveM * 64 + mi * 16 + quad * 4 + r;
            const float* xr = Xf + (size_t)b * F + blockN + waveN * 64 + l16;
            float pv = acc[mi][0][r] * xr[0]
                     + acc[mi][1][r] * xr[16]
                     + acc[mi][2][r] * xr[32]
                     + acc[mi][3][r] * xr[48];
            pv += __shfl_xor(pv, 1);
            pv += __shfl_xor(pv, 2);
            pv += __shfl_xor(pv, 4);
            pv += __shfl_xor(pv, 8);
            if (l16 == 0) atomicAdd(&rowacc[b], pv);
        }
    }
}

__global__ void sigmoid_kernel(const float* __restrict__ acc, float* __restrict__ out) {
    int b = blockIdx.x * blockDim.x + threadIdx.x;
    out[b] = 1.0f / (1.0f + __expf(-acc[b]));
}

// Correctness fallback if workspace is too small: direct per-row computation.
__global__ void fallback_kernel(const float* __restrict__ x, const float* __restrict__ w,
                                float* __restrict__ out) {
    __shared__ float xs[F];
    __shared__ float partial[4];
    const int b = blockIdx.x;
    for (int i = threadIdx.x; i < F; i += 256) xs[i] = x[(size_t)b * F + i];
    __syncthreads();
    float s = 0.0f;
    for (int i = threadIdx.x; i < F - 1; i += 256) {
        const float xi = xs[i];
        const int kbase = i * (F - 1) - (i * (i - 1)) / 2 - i - 1;
        for (int j = i + 1; j < F; j++) s += w[kbase + j] * xi * xs[j];
    }
    for (int off = 32; off; off >>= 1) s += __shfl_down(s, off);
    if ((threadIdx.x & 63) == 0) partial[threadIdx.x >> 6] = s;
    __syncthreads();
    if (threadIdx.x == 0) {
        float t = partial[0] + partial[1] + partial[2] + partial[3];
        out[b] = 1.0f / (1.0f + __expf(-t));
    }
}

extern "C" void kernel_launch(void* const* d_in, const int* in_sizes, int n_in,
                              void* d_out, int out_size, void* d_ws, size_t ws_size,
                              hipStream_t stream) {
    const float* x = (const float*)d_in[0];
    const float* w = (const float*)d_in[1];
    float* out = (float*)d_out;

    const size_t acc_bytes = 65536;                       // 16384 fp32 (rounded)
    const size_t B_bytes   = (size_t)F * F * 2;           // 2 MiB packed triangular W
    const size_t Xp_bytes  = (size_t)B_ROWS * F * 2;      // 32 MiB packed X
    const size_t needed = acc_bytes + B_bytes + Xp_bytes;

    if (ws_size < needed) {
        fallback_kernel<<<B_ROWS, 256, 0, stream>>>(x, w, out);
        return;
    }

    float*    acc = (float*)d_ws;
    ushort_t* Bp  = (ushort_t*)((char*)d_ws + acc_bytes);
    ushort_t* Xp  = (ushort_t*)((char*)d_ws + acc_bytes + B_bytes);

    // prep: 64 (acc zero) + 512 (pack B) + 8192 (pack X)
    prep_kernel<<<64 + 512 + 8192, 256, 0, stream>>>(w, x, Bp, Xp, acc);
    // 128 M-tiles x 8 N-tiles; per-block K-extent 4*(nt+1) K-steps of 32
    gemm_kernel<<<1024, 256, 0, stream>>>(Xp, Bp, x, acc);
    sigmoid_kernel<<<B_ROWS / 256, 256, 0, stream>>>(acc, out);
}

// Round 15
// 128.481 us; speedup vs baseline: 1.0173x; 1.0173x over previous
//
#include <hip/hip_runtime.h>
#include <hip/hip_bf16.h>

#define F 1024
#define B_ROWS 16384

typedef short v8s __attribute__((ext_vector_type(8)));
typedef float v4f __attribute__((ext_vector_type(4)));
typedef unsigned short v8u __attribute__((ext_vector_type(8)));
typedef unsigned short ushort_t;

__device__ __forceinline__ unsigned short f2bf(float f) {
    unsigned int u = __builtin_bit_cast(unsigned int, f);
    u = (u + 0x7FFFu + ((u >> 16) & 1u)) >> 16;  // RNE
    return (unsigned short)u;
}

// async global->LDS, 16B per lane. LDS dest = wave-uniform base + lane*16.
__device__ __forceinline__ void gload_lds16(const ushort_t* g, ushort_t* l) {
    __builtin_amdgcn_global_load_lds(
        (const __attribute__((address_space(1))) unsigned int*)g,
        (__attribute__((address_space(3))) unsigned int*)l,
        16, 0, 0);
}

// Chunk (rb, cb) = 16-row x 32-col bf16 block stored [lane][8 bf16] in MFMA
// operand order: lane l -> row rb*16 + (l&15), cols cb*32 + (l>>4)*8..+8.
// One chunk = 1 KB. B = strictly upper-triangular W ((n,k) = w_{kn}, k<n).
// N-tile nt needs K < 128*(nt+1): 56% of the full-GEMM MACs.
//
// POISON LOG (keep forever):
//  - fused-sigmoid epilogue in gemm: CONVICTED (MfmaUtil 20->4.4%). Separate.
//  - __launch_bounds__(256,4): spill on the old ping-pong loop; NEUTRAL
//    (no spill) on the m97 loop -- kept for 4 co-resident blocks/CU.
//  - X-pack fused as per-wave fp32 loads+cvts on MFMA path (r17): FAILED.
//  - K-split jobs (r18): REGRESSION -- but the regression was the +512
//    prologues/epilogues + A-refetch, NOT balance per se (see r25 below).
//  - fp32-A staged via global_load_lds + post-LDS cvt_pk (r20/r21): FAILED
//    (cvt+extra ds_reads on critical path; 4KB/lane-stride A-gather).
//    X-pack amortizes conversion AND linearizes staging -- it stays.
//  - ring-3 + counted-vmcnt barrier on the m97 loop (r23/r24): NEUTRAL-to-
//    -2us. THIRD null on schedule surgery (r16, m131-140 pattern).
//    Schedule micro-surgery is retired for this structure.
//
// r19/r22 (BEST, 128.2us): m97 structure -- both operands via
// global_load_lds from packed chunks, zero per-wave global loads in the
// loop, 2-buffer __syncthreads schedule, (256,4).
// r25 (this): nt-remap for static CU balance. Round-robin dispatch gives
// CU c blocks {c, c+256, c+512, c+768}; old map nt=7-(b>>7) summed 20 vs
// 16 K-units across CU halves (25% skew). New map: q=b>>8, h=(b&255)>>7,
// nt = {7,5,0,2,6,4,1,3}[(q<<1)|h] -> every CU sums 18; same 1024 blocks,
// zero extra work/fetch (the clean version of what r18 bungled).

// prep: [0,64) zero rowacc; [64,576) pack triangular B; [576,8768) pack X.
__global__ __launch_bounds__(256) void prep_kernel(
        const float* __restrict__ w, const float* __restrict__ x,
        ushort_t* __restrict__ Bp, ushort_t* __restrict__ Xp,
        float* __restrict__ acc) {
    const int bid  = blockIdx.x;
    const int tid  = threadIdx.x;
    const int lane = tid & 63;
    const int wave = tid >> 6;
    const int l16  = lane & 15;
    const int quad = lane >> 4;

    if (bid < 64) {
        acc[bid * 256 + tid] = 0.0f;
    } else if (bid < 576) {
        const int c  = (bid - 64) * 4 + wave;    // 0..2047
        const int n  = (c >> 5) * 16 + l16;      // output-col axis
        const int k0 = (c & 31) * 32 + quad * 8; // contraction axis
        v8u o;
#pragma unroll
        for (int e = 0; e < 8; ++e) {
            const int k = k0 + e;
            float v = 0.0f;
            if (k < n) {  // strictly upper: pair (k,n), k<n
                const int idx = k * (F - 1) - (k * (k - 1)) / 2 + (n - k - 1);
                v = w[idx];  // scattered read; w = 2MB, L2-resident
            }
            o[e] = f2bf(v);
        }
        *(v8u*)(Bp + (size_t)c * 512 + lane * 8) = o;
    } else {
        const int c  = (bid - 576) * 4 + wave;  // 0..32767
        const int r  = (c >> 5) * 16 + l16;     // X row
        const int k0 = (c & 31) * 32 + quad * 8;
        const float* src = x + (size_t)r * F + k0;
        float4 v0 = *(const float4*)(src);
        float4 v1 = *(const float4*)(src + 4);
        v8u o;
        o[0] = f2bf(v0.x); o[1] = f2bf(v0.y); o[2] = f2bf(v0.z); o[3] = f2bf(v0.w);
        o[4] = f2bf(v1.x); o[5] = f2bf(v1.y); o[6] = f2bf(v1.z); o[7] = f2bf(v1.w);
        *(v8u*)(Xp + (size_t)c * 512 + lane * 8) = o;
    }
}

// m97-structure GEMM, triangular-K, CU-balanced nt-remap (r25).
// 128x128 block, 2x2 waves, K-step 32.
// LDS: 2 bufs x (8 A-chunks + 8 B-chunks) x 1KB = 32 KB.
__global__ __launch_bounds__(256, 4) void gemm_kernel(
        const ushort_t* __restrict__ Xp,   // packed X chunks
        const ushort_t* __restrict__ Bp,   // packed triangular-W chunks
        const float*   __restrict__ Xf,    // fp32 X (epilogue)
        float*         __restrict__ rowacc) {
    __shared__ ushort_t Ls[2 * 16 * 512];  // [buf][slot 0-7=A, 8-15=B][1KB]

    const int b   = blockIdx.x;          // 0..1023
    const int q   = b >> 8;              // quarter 0..3 (CU round q)
    const int r   = b & 255;             // CU id under round-robin dispatch
    const int h   = r >> 7;              // CU half
    // Balanced nt table: per-CU sums (q=0..3) = 18 K-units for both halves;
    // each (M-tile, nt) covered exactly once across q.
    const int NT[8] = {7, 5, 0, 2, 6, 4, 1, 3};
    const int nt  = NT[(q << 1) | h];
    const int xcd = r & 7;
    const int y   = (r >> 3) & 15;
    const int blockM = (xcd * 16 + y) * 128;
    const int blockN = nt * 128;
    const int tEnd   = 4 * (nt + 1);     // K-steps of 32: K < 128*(nt+1)

    const int tid   = threadIdx.x;
    const int lane  = tid & 63;
    const int wave  = tid >> 6;
    const int waveM = wave >> 1;
    const int waveN = wave & 1;
    const int quad  = lane >> 4;
    const int l16   = lane & 15;

    const int mgBase = blockM >> 4;      // first A row-group (of 8)
    const int ngB    = nt * 8;           // first B row-group (of 8)

    // Staging: waves 0-1 stage the 8 A-chunks, waves 2-3 the 8 B-chunks.
    // Per wave 4 gload_lds16 per K-step; wave-uniform LDS dest + lane*16.
    const bool stageA = (wave < 2);
    const int  qBase  = (wave & 1) * 4;  // chunk offset within A or B half
    const ushort_t* gsrc0 = stageA
        ? Xp + ((size_t)(mgBase + qBase) * 32) * 512
        : Bp + ((size_t)(ngB  + qBase) * 32) * 512;
    const int slot0 = (stageA ? 0 : 8) + qBase;

#define STAGE(t, buf)                                                          \
    {                                                                          \
        _Pragma("unroll")                                                      \
        for (int qq = 0; qq < 4; ++qq) {                                       \
            gload_lds16(gsrc0 + ((size_t)qq * 32 + (t)) * 512 + lane * 8,      \
                        Ls + ((buf) * 16 + slot0 + qq) * 512);                 \
        }                                                                      \
    }

    v4f acc[4][4];
#pragma unroll
    for (int i = 0; i < 4; i++)
#pragma unroll
        for (int j = 0; j < 4; j++) acc[i][j] = (v4f)(0.0f);

    v8s afr[4], bfr[4];

    // prologue: stage K-step 0
    STAGE(0, 0)
    __syncthreads();

    for (int t = 0; t < tEnd; ++t) {
        const int  buf  = t & 1;
        const bool more = (t + 1 < tEnd);
        if (more) STAGE(t + 1, buf ^ 1)  // in flight across this step

#pragma unroll
        for (int mi = 0; mi < 4; ++mi)
            afr[mi] = *(const v8s*)(Ls + (buf * 16 + waveM * 4 + mi) * 512 + lane * 8);
#pragma unroll
        for (int ni = 0; ni < 4; ++ni)
            bfr[ni] = *(const v8s*)(Ls + (buf * 16 + 8 + waveN * 4 + ni) * 512 + lane * 8);

#pragma unroll
        for (int mi = 0; mi < 4; ++mi)
#pragma unroll
            for (int ni = 0; ni < 4; ++ni)
                acc[mi][ni] = __builtin_amdgcn_mfma_f32_16x16x32_bf16(
                    afr[mi], bfr[ni], acc[mi][ni], 0, 0, 0);

        if (more) __syncthreads();  // gates buffer reuse; staging t+1 landed
    }
#undef STAGE

    // Epilogue: C/D mapping (verified): col = lane&15, row = quad*4 + reg.
#pragma unroll
    for (int mi = 0; mi < 4; mi++) {
#pragma unroll
        for (int rr = 0; rr < 4; rr++) {
            const int bb = blockM + waveM * 64 + mi * 16 + quad * 4 + rr;
            const float* xr = Xf + (size_t)bb * F + blockN + waveN * 64 + l16;
            float pv = acc[mi][0][rr] * xr[0]
                     + acc[mi][1][rr] * xr[16]
                     + acc[mi][2][rr] * xr[32]
                     + acc[mi][3][rr] * xr[48];
            pv += __shfl_xor(pv, 1);
            pv += __shfl_xor(pv, 2);
            pv += __shfl_xor(pv, 4);
            pv += __shfl_xor(pv, 8);
            if (l16 == 0) atomicAdd(&rowacc[bb], pv);
        }
    }
}

__global__ void sigmoid_kernel(const float* __restrict__ acc, float* __restrict__ out) {
    int b = blockIdx.x * blockDim.x + threadIdx.x;
    out[b] = 1.0f / (1.0f + __expf(-acc[b]));
}

// Correctness fallback if workspace is too small: direct per-row computation.
__global__ void fallback_kernel(const float* __restrict__ x, const float* __restrict__ w,
                                float* __restrict__ out) {
    __shared__ float xs[F];
    __shared__ float partial[4];
    const int b = blockIdx.x;
    for (int i = threadIdx.x; i < F; i += 256) xs[i] = x[(size_t)b * F + i];
    __syncthreads();
    float s = 0.0f;
    for (int i = threadIdx.x; i < F - 1; i += 256) {
        const float xi = xs[i];
        const int kbase = i * (F - 1) - (i * (i - 1)) / 2 - i - 1;
        for (int j = i + 1; j < F; j++) s += w[kbase + j] * xi * xs[j];
    }
    for (int off = 32; off; off >>= 1) s += __shfl_down(s, off);
    if ((threadIdx.x & 63) == 0) partial[threadIdx.x >> 6] = s;
    __syncthreads();
    if (threadIdx.x == 0) {
        float t = partial[0] + partial[1] + partial[2] + partial[3];
        out[b] = 1.0f / (1.0f + __expf(-t));
    }
}

extern "C" void kernel_launch(void* const* d_in, const int* in_sizes, int n_in,
                              void* d_out, int out_size, void* d_ws, size_t ws_size,
                              hipStream_t stream) {
    const float* x = (const float*)d_in[0];
    const float* w = (const float*)d_in[1];
    float* out = (float*)d_out;

    const size_t acc_bytes = 65536;                       // 16384 fp32 (rounded)
    const size_t B_bytes   = (size_t)F * F * 2;           // 2 MiB packed triangular W
    const size_t Xp_bytes  = (size_t)B_ROWS * F * 2;      // 32 MiB packed X
    const size_t needed = acc_bytes + B_bytes + Xp_bytes;

    if (ws_size < needed) {
        fallback_kernel<<<B_ROWS, 256, 0, stream>>>(x, w, out);
        return;
    }

    float*    acc = (float*)d_ws;
    ushort_t* Bp  = (ushort_t*)((char*)d_ws + acc_bytes);
    ushort_t* Xp  = (ushort_t*)((char*)d_ws + acc_bytes + B_bytes);

    // prep: 64 (acc zero) + 512 (pack B) + 8192 (pack X)
    prep_kernel<<<64 + 512 + 8192, 256, 0, stream>>>(w, x, Bp, Xp, acc);
    // 128 M-tiles x 8 N-tiles, CU-balanced nt assignment (18 K-units/CU)
    gemm_kernel<<<1024, 256, 0, stream>>>(Xp, Bp, x, acc);
    sigmoid_kernel<<<B_ROWS / 256, 256, 0, stream>>>(acc, out);
}